// Round 7
// baseline (114.147 us; speedup 1.0000x reference)
//
#include <hip/hip_runtime.h>

// shGLM: 20-subunit tree GLM, T=10000 — ONE persistent kernel, 3 phases:
//  P1: synapse class sums sig[s][t]  (global_load_lds staging, r5-proven body)
//  P2: 201-tap conv -> subT[s][t]    (register-blocked FIR, r5-proven body)
//  P3: chunked tree scan             (CHUNK=20, WARM=24, ring-free, skew=4)
// Grid-wide sync: 512 blocks x 256 thr, 2 blocks/CU co-resident
// (launch_bounds(256,2), 32KB LDS/block), tree barrier with agent-scope
// atomics + s_sleep spin (timeout -> never hangs). Counters zeroed per call
// via hipMemsetAsync node. Cross-XCD: writer __threadfence (L2 wb) before
// counter add; spin load is ACQUIRE/AGENT (L2 inv); data is first-touch.
// ws: [0,800000) subT, [800000,1600000) sig, [1600000,+8192) barrier ctrs

#define T_LEN   10000
#define NSYN    2000
#define SUBS    20
#define KLEN    201
#define NPERS   512
#define CHUNK   20
#define K3BLK   500          // 500*20 = 10000 exactly
#define WARM    24
#define NITER   (CHUNK + WARM + 16)   // 60  (<=100: ring-free validity)
#define NQUAD   (NITER / 4)           // 15
#define OUT_N0  (WARM + 16)           // 40
#define LPITCH  124
#define CTR_OFF 1600000

__device__ __forceinline__ float fexp2(float x) {
#if __has_builtin(__builtin_amdgcn_exp2f)
  return __builtin_amdgcn_exp2f(x);
#else
  return exp2f(x);
#endif
}
__device__ __forceinline__ float frcp(float x) {
#if __has_builtin(__builtin_amdgcn_rcpf)
  return __builtin_amdgcn_rcpf(x);
#else
  return 1.0f / x;
#endif
}
__device__ __forceinline__ float rfl(float x) {
  return __int_as_float(__builtin_amdgcn_readfirstlane(__float_as_int(x)));
}

typedef __attribute__((address_space(3))) uint32_t lds_u32;
typedef const __attribute__((address_space(1))) uint32_t g_u32;

// tree barrier: 16 groups of 32 blocks -> root; timeout spin (no hang)
__device__ __forceinline__ void gbar(unsigned* c, int bid, int tid) {
  __syncthreads();
  if (tid == 0) {
    __threadfence();                       // agent release: L2 writeback
    unsigned old = __hip_atomic_fetch_add(&c[(bid >> 5) * 32], 1u,
                                          __ATOMIC_ACQ_REL, __HIP_MEMORY_SCOPE_AGENT);
    if (old == 31u)
      __hip_atomic_fetch_add(&c[512], 1u, __ATOMIC_ACQ_REL, __HIP_MEMORY_SCOPE_AGENT);
    int lim = 8000000;
    while (__hip_atomic_load(&c[512], __ATOMIC_ACQUIRE, __HIP_MEMORY_SCOPE_AGENT) < 16u
           && --lim)
      __builtin_amdgcn_s_sleep(2);
  }
  __syncthreads();
}

__global__ __launch_bounds__(256, 2) void fused_shglm(
    const float* __restrict__ X, const float* __restrict__ V_o,
    const float* __restrict__ K_syn, const float* __restrict__ sbt,
    const float* __restrict__ Delta, const float* __restrict__ C,
    const float* __restrict__ Theta, const float* __restrict__ thresh,
    const float* __restrict__ tscale, const float* __restrict__ ssize,
    const float* __restrict__ hbt, const float* __restrict__ K_hist,
    float* __restrict__ out, float* __restrict__ subT,
    float* __restrict__ sig, unsigned* __restrict__ ctr) {
  __shared__ __align__(16) char pool[32768];
  const int tid = threadIdx.x;
  const int bid = blockIdx.x;

  // ================= Phase 1: class sums (r5 body, grid-strided) ==========
  {
    float* xrow = (float*)pool;
    const float4* Xv = (const float4*)X;
    const int wave = tid >> 6, lane = tid & 63;
    for (int rb = bid * 4; rb < T_LEN; rb += NPERS * 4) {
      const size_t rowbase = (size_t)rb * 500;   // float4 units
#pragma unroll
      for (int k = 0; k < 8; ++k) {
        size_t gidx = rowbase + (size_t)(tid + 256 * k);
        if (gidx > 4999999u) gidx = 4999999u;    // clamp at X tail
        unsigned ldsoff = (unsigned)((wave * 64 + 256 * k) * 16);  // wave-uniform
        __builtin_amdgcn_global_load_lds((g_u32*)(Xv + gidx),
                                         (lds_u32*)(uint32_t*)(pool + ldsoff),
                                         16, 0, 0);
      }
      __syncthreads();                           // drains vmcnt
      const float* row = xrow + wave * NSYN;
      float acc = 0.f;
      if (lane < 60) {
#pragma unroll
        for (int k = 0; k < 33; ++k) acc += row[lane + 60 * k];
      }
      if (lane < 20) acc += row[1980 + lane];
      float a1 = __shfl(acc, (lane + 20 < 64) ? lane + 20 : 63);
      float a2 = __shfl(acc, (lane + 40 < 64) ? lane + 40 : 63);
      if (lane < 20) sig[(size_t)lane * T_LEN + rb + wave] = acc + a1 + a2;
      __syncthreads();                           // protect LDS before next sweep
    }
  }

  gbar(ctr, bid, tid);          // ---- barrier A: sig complete ----

  // ================= Phase 2: FIR conv (r5 4-out body) ====================
  if ((bid & 1) == 0 && bid < 400) {             // 200 items on even bids
    const int item = bid >> 1;                   // item = s*10 + cx
    const int s = item / 10;
    const int t0 = (item - s * 10) * 1024;
    float* wsig = (float*)pool;                  // 1232 floats
    float* kern = (float*)(pool + 4928);         // 208 floats, 16B-aligned
    const float delta = __expf(Delta[0]);
    const float it0 = __expf(-sbt[0]);
    const float it1 = __expf(-sbt[1]);
    const int c = (s % 5 == 0) ? 1 : 0;
    const float ka = K_syn[s * 4 + c];
    const float kb = K_syn[s * 4 + 2 + c];
    if (tid < 208) {
      float val = 0.f;
      if (tid < KLEN) {
        float te = fmaxf((float)tid - delta, 0.f);
        float ta = te * it0, tb = te * it1;
        val = ka * (ta * __expf(-ta)) + kb * (tb * __expf(-tb));
      }
      kern[tid] = val;
    }
    const float* srow = sig + (size_t)s * T_LEN;
#pragma unroll
    for (int k = 0; k < 5; ++k) {
      int e = tid + 256 * k;
      if (e < 1232) {
        int col = t0 - 100 + e;
        wsig[e] = (e < 1224 && col >= 0 && col < T_LEN) ? srow[col] : 0.f;
      }
    }
    __syncthreads();
    const float4* wv = (const float4*)wsig;
    float4 qA = wv[tid], qB = wv[tid + 1];
    float a0 = 0.f, a1 = 0.f, a2 = 0.f, a3 = 0.f;
#pragma unroll
    for (int g = 0; g < 51; ++g) {
      float4 kv = *(const float4*)&kern[4 * g];
      float4 qC = wv[tid + g + 2];
      a0 = fmaf(kv.x, qA.x, fmaf(kv.y, qA.y, fmaf(kv.z, qA.z, fmaf(kv.w, qA.w, a0))));
      a1 = fmaf(kv.x, qA.y, fmaf(kv.y, qA.z, fmaf(kv.z, qA.w, fmaf(kv.w, qB.x, a1))));
      a2 = fmaf(kv.x, qA.z, fmaf(kv.y, qA.w, fmaf(kv.z, qB.x, fmaf(kv.w, qB.y, a2))));
      a3 = fmaf(kv.x, qA.w, fmaf(kv.y, qB.x, fmaf(kv.z, qB.y, fmaf(kv.w, qB.z, a3))));
      qA = qB; qB = qC;
    }
    int t = t0 + 4 * tid;
    if (t < T_LEN) {
      float4 o; o.x = a0; o.y = a1; o.z = a2; o.w = a3;
      *(float4*)(subT + (size_t)s * T_LEN + t) = o;
    }
  }

  gbar(ctr + 1024, bid, tid);   // ---- barrier B: subT complete ----

  // ================= Phase 3: chunked tree scan ===========================
  if (bid < K3BLK) {
    float* lds_subT = (float*)pool;              // 20 x 124 floats
    const int b = bid;
    const int t_start = b * CHUNK - WARM;        // multiple of 4
    // stage cols [t_start-16, t_start+108) with all 256 threads
#pragma unroll
    for (int k = 0; k < 3; ++k) {
      int i = tid + 256 * k;
      if (i < 620) {                             // 20 rows x 31 float4
        int ss = i / 31, q = i - ss * 31;
        int col = t_start - 16 + 4 * q;
        col = (col < 0) ? 0 : ((col > 9996) ? 9996 : col);
        *(float4*)&lds_subT[ss * LPITCH + 4 * q] =
            *(const float4*)(subT + (size_t)ss * T_LEN + col);
      }
    }
    __syncthreads();
    if (tid < 64) {
      const int lane = tid;
      const int s = (lane < SUBS) ? lane : SUBS - 1;
      const float Vo = V_o[0];
      const float L2E = 1.4426950408889634f;
      float eC = __expf(C[s]);
      float szC = ssize[s];
      const float thL = Theta[s] * L2E;
      const float aspk = -tscale[s] * L2E;
      const float bspk = thresh[s] * L2E;
      float k0 = K_hist[s * 3 + 0], k1 = K_hist[s * 3 + 1], k2 = K_hist[s * 3 + 2];
      if (lane >= SUBS) { eC = 0.f; k0 = 0.f; k1 = 0.f; k2 = 0.f; }
      szC *= eC;
      float rho0, rho1, rho2, rt0, rt1, rt2;
      {
        float it, rr;
        it = __expf(-hbt[0]); rr = __expf(-it); rho0 = rfl(rr); rt0 = rfl(rr * it);
        it = __expf(-hbt[1]); rr = __expf(-it); rho1 = rfl(rr); rt1 = rfl(rr * it);
        it = __expf(-hbt[2]); rr = __expf(-it); rho2 = rfl(rr); rt2 = rfl(rr * it);
      }
      const int d = 31 - __clz(s + 1);           // depth 0..4
      const int skew = 4 * (4 - d);              // root 16, leaves 0
      const int cl = (2 * lane + 1 < 64) ? 2 * lane + 1 : 63;
      const int cr = (2 * lane + 2 < 64) ? 2 * lane + 2 : 63;
      int t = t_start - skew;

      float F0 = 0, F1 = 0, F2 = 0, G0 = 0, G1 = 0, G2 = 0;
      float pL0 = 0, pL1 = 0, pL2 = 0, pL3 = 0;
      float pR0 = 0, pR1 = 0, pR2 = 0, pR3 = 0;
      float nL0, nL1, nL2, nL3, nR0, nR1, nR2, nR3;
      const int subbase = s * LPITCH + (16 - skew);
      float4 subq = *(const float4*)&lds_subT[subbase];

#define STEP(J, SUBV, PLV, PRV)                                             \
  {                                                                         \
    float conv = fmaf(k0, F0, fmaf(k1, F1, k2 * F2));                       \
    float pre = (SUBV + conv) + (PLV + PRV);                                \
    float u = fexp2(fmaf(pre, -L2E, thL));                                  \
    float post = frcp(1.f + u);                                             \
    float v = fexp2(fmaf(post, aspk, bspk));                                \
    float spk = frcp(1.f + v);                                              \
    spk = ((t + J) < 0) ? 0.f : spk;                                        \
    F0 = fmaf(rho0, F0, rt0 * G0);                                          \
    F1 = fmaf(rho1, F1, rt1 * G1);                                          \
    F2 = fmaf(rho2, F2, rt2 * G2);                                          \
    G0 = fmaf(rho0, G0, spk);                                               \
    G1 = fmaf(rho1, G1, spk);                                               \
    G2 = fmaf(rho2, G2, spk);                                               \
    float y = fmaf(spk, szC, post * eC);                                    \
    if ((n + J) >= OUT_N0) {                                                \
      if (lane == 0) out[t + J] = y + Vo;                                   \
    }                                                                       \
    nL##J = __shfl(y, cl);                                                  \
    nR##J = __shfl(y, cr);                                                  \
  }

      for (int n4 = 0; n4 < NQUAD; ++n4) {
        const int n = n4 << 2;
        float4 subq_n = *(const float4*)&lds_subT[subbase + n + 4];
        STEP(0, subq.x, pL0, pR0)
        STEP(1, subq.y, pL1, pR1)
        STEP(2, subq.z, pL2, pR2)
        STEP(3, subq.w, pL3, pR3)
        subq = subq_n;
        pL0 = nL0; pL1 = nL1; pL2 = nL2; pL3 = nL3;
        pR0 = nR0; pR1 = nR1; pR2 = nR2; pR3 = nR3;
        t += 4;
      }
#undef STEP
    }
  }
}

extern "C" void kernel_launch(void* const* d_in, const int* in_sizes, int n_in,
                              void* d_out, int out_size, void* d_ws, size_t ws_size,
                              hipStream_t stream) {
  (void)in_sizes; (void)n_in; (void)out_size; (void)ws_size;
  const float* X      = (const float*)d_in[0];
  const float* V_o    = (const float*)d_in[1];
  const float* K_syn  = (const float*)d_in[2];
  const float* sbt    = (const float*)d_in[3];
  const float* Delta  = (const float*)d_in[4];
  const float* C      = (const float*)d_in[5];
  const float* Theta  = (const float*)d_in[6];
  const float* thr    = (const float*)d_in[7];
  const float* tsc    = (const float*)d_in[8];
  const float* ssz    = (const float*)d_in[9];
  const float* hbt    = (const float*)d_in[10];
  const float* K_hist = (const float*)d_in[11];
  float* out   = (float*)d_out;
  float* subT  = (float*)d_ws;                           // 800000 B
  float* sig   = (float*)((char*)d_ws + 800000);         // 800000 B
  unsigned* ctr = (unsigned*)((char*)d_ws + CTR_OFF);    // 8192 B

  hipMemsetAsync((void*)ctr, 0, 8192, stream);
  hipLaunchKernelGGL(fused_shglm, dim3(NPERS), dim3(256), 0, stream,
                     X, V_o, K_syn, sbt, Delta, C, Theta, thr, tsc, ssz,
                     hbt, K_hist, out, subT, sig, ctr);
}

// Round 8
// 35.191 us; speedup vs baseline: 3.2436x; 3.2436x over previous
//
#include <hip/hip_runtime.h>

// shGLM: 20-subunit tree GLM, T=10000 — TWO kernels:
//  A (k1): synapse class sums sig[s][t] — r5-proven global_load_lds body,
//          2500 blocks (deep queue => HBM-bound pipelining).
//  B (k23): fused conv+scan, 250 blocks x 256 thr: each block FIR-computes its
//          own 20x100 subT tile in LDS from sig (out[lr]=Σ kern[τ]·sigw[lr+τ]),
//          then threads 0-63 run the proven chunked tree scan.
//          CHUNK=40, WARM=24 (validated r7), NITER=80 <= 100 (ring-free).
// ws: [800000, 1600000) sig (20 x 10000 f32)   ([0,800000) unused now)

#define T_LEN   10000
#define NSYN    2000
#define SUBS    20
#define KLEN    201
#define CHUNK   40
#define NBLK    250          // 250*40 = 10000 exactly
#define WARM    24
#define NITER   (CHUNK + WARM + 16)   // 80  (<=100: ring-free validity)
#define NQUAD   (NITER / 4)           // 20
#define OUT_N0  (WARM + 16)           // 40
#define LPITCH  100                   // subT tile pitch (floats)
#define SGP     308                   // sig window pitch (floats, mult 4)
#define KP      208                   // kern pitch (floats, 832B = mult 16)

__device__ __forceinline__ float fexp2(float x) {
#if __has_builtin(__builtin_amdgcn_exp2f)
  return __builtin_amdgcn_exp2f(x);
#else
  return exp2f(x);
#endif
}
__device__ __forceinline__ float frcp(float x) {
#if __has_builtin(__builtin_amdgcn_rcpf)
  return __builtin_amdgcn_rcpf(x);
#else
  return 1.0f / x;
#endif
}
__device__ __forceinline__ float rfl(float x) {
  return __int_as_float(__builtin_amdgcn_readfirstlane(__float_as_int(x)));
}

typedef __attribute__((address_space(3))) uint32_t lds_u32;
typedef const __attribute__((address_space(1))) uint32_t g_u32;

// ---------------- A: class sums, global_load_lds staging (r5 body) -------
__global__ __launch_bounds__(256) void k1_classsum(const float* __restrict__ X,
                                                   float* __restrict__ sig) {
  __shared__ __align__(16) float xrow[8192];   // 32 KB; floats 8000..8191 scratch
  const int tid = threadIdx.x;
  const int t_base = blockIdx.x * 4;
  const size_t rowbase = (size_t)t_base * 500;   // in float4 units
  const int wave = tid >> 6, lane = tid & 63;
  const float4* Xv = (const float4*)X;
#pragma unroll
  for (int k = 0; k < 8; ++k) {
    size_t gidx = rowbase + (size_t)(tid + 256 * k);
    if (gidx > 4999999u) gidx = 4999999u;        // clamp at X tail -> scratch slots
    unsigned ldsoff = (unsigned)((wave * 64 + 256 * k) * 16);  // wave-uniform
    __builtin_amdgcn_global_load_lds(
        (g_u32*)(Xv + gidx),
        (lds_u32*)(uint32_t*)((char*)xrow + ldsoff),
        16, 0, 0);
  }
  __syncthreads();   // drains vmcnt before barrier

  const float* row = xrow + wave * NSYN;
  float acc = 0.f;
  if (lane < 60) {
#pragma unroll
    for (int k = 0; k < 33; ++k) acc += row[lane + 60 * k];
  }
  if (lane < 20) acc += row[1980 + lane];
  float a1 = __shfl(acc, (lane + 20 < 64) ? lane + 20 : 63);
  float a2 = __shfl(acc, (lane + 40 < 64) ? lane + 40 : 63);
  if (lane < 20) sig[(size_t)lane * T_LEN + t_base + wave] = acc + a1 + a2;
}

// ---------------- B: fused conv + chunked tree scan ----------------------
__global__ __launch_bounds__(256) void k23_fused(
    const float* __restrict__ sig, const float* __restrict__ V_o,
    const float* __restrict__ K_syn, const float* __restrict__ sbt,
    const float* __restrict__ Delta, const float* __restrict__ C,
    const float* __restrict__ Theta, const float* __restrict__ thresh,
    const float* __restrict__ tscale, const float* __restrict__ ssize,
    const float* __restrict__ hbt, const float* __restrict__ K_hist,
    float* __restrict__ out) {
  __shared__ __align__(16) float sigw[SUBS * SGP];     // 24640 B
  __shared__ __align__(16) float kern[SUBS * KP];      // 16640 B
  __shared__ __align__(16) float lds_subT[SUBS * LPITCH];  // 8000 B
  const int tid = threadIdx.x;
  const int b = blockIdx.x;
  const int t_start = b * CHUNK - WARM;      // multiple of 4

  // ---- stage sig window: rows s, cols [t_start-116, t_start+192) ----
  {
    const int col0 = t_start - 116;          // multiple of 4
    for (int i = tid; i < SUBS * 77; i += 256) {
      int s = i / 77, f4 = i - s * 77;
      int col = col0 + 4 * f4;
      float4 v = {0.f, 0.f, 0.f, 0.f};
      if (col >= 0 && col < T_LEN)
        v = *(const float4*)(sig + (size_t)s * T_LEN + col);
      *(float4*)&sigw[s * SGP + 4 * f4] = v;
    }
  }
  // ---- build per-subunit kernels ----
  {
    const float delta = __expf(Delta[0]);
    const float it0 = __expf(-sbt[0]);
    const float it1 = __expf(-sbt[1]);
    for (int i = tid; i < SUBS * KP; i += 256) {
      int s = i / KP, k = i - s * KP;
      float val = 0.f;
      if (k < KLEN) {
        int c = (s % 5 == 0) ? 1 : 0;
        float te = fmaxf((float)k - delta, 0.f);
        float ta = te * it0, tb = te * it1;
        val = K_syn[s * 4 + c] * (ta * __expf(-ta)) +
              K_syn[s * 4 + 2 + c] * (tb * __expf(-tb));
      }
      kern[i] = val;
    }
  }
  __syncthreads();

  // ---- conv: 500 items (s-major: item = s*25+q), 4 outputs each ----
#pragma unroll
  for (int pass = 0; pass < 2; ++pass) {
    int it = tid + 256 * pass;
    if (it < 500) {
      int s = it / 25, q = it - s * 25;
      const float4* wvs = (const float4*)&sigw[s * SGP];
      const float4* kern4 = (const float4*)&kern[s * KP];
      float4 qA = wvs[q], qB = wvs[q + 1];
      float a0 = 0.f, a1 = 0.f, a2 = 0.f, a3 = 0.f;
#pragma unroll
      for (int g = 0; g < 51; ++g) {
        float4 kv = kern4[g];
        float4 qC = wvs[q + g + 2];
        a0 = fmaf(kv.x, qA.x, fmaf(kv.y, qA.y, fmaf(kv.z, qA.z, fmaf(kv.w, qA.w, a0))));
        a1 = fmaf(kv.x, qA.y, fmaf(kv.y, qA.z, fmaf(kv.z, qA.w, fmaf(kv.w, qB.x, a1))));
        a2 = fmaf(kv.x, qA.z, fmaf(kv.y, qA.w, fmaf(kv.z, qB.x, fmaf(kv.w, qB.y, a2))));
        a3 = fmaf(kv.x, qA.w, fmaf(kv.y, qB.x, fmaf(kv.z, qB.y, fmaf(kv.w, qB.z, a3))));
        qA = qB; qB = qC;
      }
      float4 o; o.x = a0; o.y = a1; o.z = a2; o.w = a3;
      *(float4*)&lds_subT[s * LPITCH + 4 * q] = o;   // rows [t_start-16+4q ..]
    }
  }
  __syncthreads();

  // ---- scan: threads 0..63, proven STEP body ----
  if (tid < 64) {
    const int lane = tid;
    const int s = (lane < SUBS) ? lane : SUBS - 1;
    const float Vo = V_o[0];
    const float L2E = 1.4426950408889634f;
    float eC = __expf(C[s]);
    float szC = ssize[s];
    const float thL = Theta[s] * L2E;
    const float aspk = -tscale[s] * L2E;
    const float bspk = thresh[s] * L2E;
    float k0 = K_hist[s * 3 + 0], k1 = K_hist[s * 3 + 1], k2 = K_hist[s * 3 + 2];
    if (lane >= SUBS) { eC = 0.f; k0 = 0.f; k1 = 0.f; k2 = 0.f; }
    szC *= eC;
    float rho0, rho1, rho2, rt0, rt1, rt2;
    {
      float it, rr;
      it = __expf(-hbt[0]); rr = __expf(-it); rho0 = rfl(rr); rt0 = rfl(rr * it);
      it = __expf(-hbt[1]); rr = __expf(-it); rho1 = rfl(rr); rt1 = rfl(rr * it);
      it = __expf(-hbt[2]); rr = __expf(-it); rho2 = rfl(rr); rt2 = rfl(rr * it);
    }
    const int d = 31 - __clz(s + 1);           // depth 0..4
    const int skew = 4 * (4 - d);              // root 16, leaves 0
    const int cl = (2 * lane + 1 < 64) ? 2 * lane + 1 : 63;
    const int cr = (2 * lane + 2 < 64) ? 2 * lane + 2 : 63;
    int t = t_start - skew;

    float F0 = 0, F1 = 0, F2 = 0, G0 = 0, G1 = 0, G2 = 0;
    float pL0 = 0, pL1 = 0, pL2 = 0, pL3 = 0;
    float pR0 = 0, pR1 = 0, pR2 = 0, pR3 = 0;
    float nL0, nL1, nL2, nL3, nR0, nR1, nR2, nR3;
    const int subbase = s * LPITCH + (16 - skew);   // mult of 4: aligned
    float4 subq = *(const float4*)&lds_subT[subbase];

#define STEP(J, SUBV, PLV, PRV)                                             \
  {                                                                         \
    float conv = fmaf(k0, F0, fmaf(k1, F1, k2 * F2));                       \
    float pre = (SUBV + conv) + (PLV + PRV);                                \
    float u = fexp2(fmaf(pre, -L2E, thL));                                  \
    float post = frcp(1.f + u);                                             \
    float v = fexp2(fmaf(post, aspk, bspk));                                \
    float spk = frcp(1.f + v);                                              \
    spk = ((t + J) < 0) ? 0.f : spk;                                        \
    F0 = fmaf(rho0, F0, rt0 * G0);                                          \
    F1 = fmaf(rho1, F1, rt1 * G1);                                          \
    F2 = fmaf(rho2, F2, rt2 * G2);                                          \
    G0 = fmaf(rho0, G0, spk);                                               \
    G1 = fmaf(rho1, G1, spk);                                               \
    G2 = fmaf(rho2, G2, spk);                                               \
    float y = fmaf(spk, szC, post * eC);                                    \
    if ((n + J) >= OUT_N0) {                                                \
      if (lane == 0) out[t + J] = y + Vo;                                   \
    }                                                                       \
    nL##J = __shfl(y, cl);                                                  \
    nR##J = __shfl(y, cr);                                                  \
  }

    for (int n4 = 0; n4 < NQUAD; ++n4) {
      const int n = n4 << 2;
      float4 subq_n = *(const float4*)&lds_subT[subbase + n + 4];
      STEP(0, subq.x, pL0, pR0)
      STEP(1, subq.y, pL1, pR1)
      STEP(2, subq.z, pL2, pR2)
      STEP(3, subq.w, pL3, pR3)
      subq = subq_n;
      pL0 = nL0; pL1 = nL1; pL2 = nL2; pL3 = nL3;
      pR0 = nR0; pR1 = nR1; pR2 = nR2; pR3 = nR3;
      t += 4;
    }
#undef STEP
  }
}

extern "C" void kernel_launch(void* const* d_in, const int* in_sizes, int n_in,
                              void* d_out, int out_size, void* d_ws, size_t ws_size,
                              hipStream_t stream) {
  (void)in_sizes; (void)n_in; (void)out_size; (void)ws_size;
  const float* X      = (const float*)d_in[0];
  const float* V_o    = (const float*)d_in[1];
  const float* K_syn  = (const float*)d_in[2];
  const float* sbt    = (const float*)d_in[3];
  const float* Delta  = (const float*)d_in[4];
  const float* C      = (const float*)d_in[5];
  const float* Theta  = (const float*)d_in[6];
  const float* thr    = (const float*)d_in[7];
  const float* tsc    = (const float*)d_in[8];
  const float* ssz    = (const float*)d_in[9];
  const float* hbt    = (const float*)d_in[10];
  const float* K_hist = (const float*)d_in[11];
  float* out = (float*)d_out;
  float* sig = (float*)((char*)d_ws + 800000);        // 800000 B

  hipLaunchKernelGGL(k1_classsum, dim3(T_LEN / 4), dim3(256), 0, stream, X, sig);
  hipLaunchKernelGGL(k23_fused, dim3(NBLK), dim3(256), 0, stream,
                     sig, V_o, K_syn, sbt, Delta, C, Theta, thr, tsc, ssz,
                     hbt, K_hist, out);
}

// Round 9
// 35.188 us; speedup vs baseline: 3.2439x; 1.0001x over previous
//
#include <hip/hip_runtime.h>

// shGLM: 20-subunit tree GLM, T=10000 — TWO kernels:
//  A (k1): synapse class sums sig[s][t]. Per-WAVE independent: wave w stages
//          row t_base+w via 8x global_load_lds into its own 8KB LDS quarter,
//          waits its own vmcnt(0) (no block barrier on the load path),
//          reduces, then one cheap barrier + wave0 does float4 stores.
//  B (k23): fused conv+scan (r8-proven verbatim): 250 blocks FIR-compute a
//          20x100 subT tile in LDS from sig, threads 0-63 run the tree scan.
//          CHUNK=40, WARM=24, NITER=80 <= 100 (ring-free).
// ws: [800000, 1600000) sig (20 x 10000 f32)

#define T_LEN   10000
#define NSYN    2000
#define SUBS    20
#define KLEN    201
#define CHUNK   40
#define NBLK    250          // 250*40 = 10000 exactly
#define WARM    24
#define NITER   (CHUNK + WARM + 16)   // 80  (<=100: ring-free validity)
#define NQUAD   (NITER / 4)           // 20
#define OUT_N0  (WARM + 16)           // 40
#define LPITCH  100                   // subT tile pitch (floats)
#define SGP     308                   // sig window pitch (floats, mult 4)
#define KP      208                   // kern pitch (floats, 832B = mult 16)

__device__ __forceinline__ float fexp2(float x) {
#if __has_builtin(__builtin_amdgcn_exp2f)
  return __builtin_amdgcn_exp2f(x);
#else
  return exp2f(x);
#endif
}
__device__ __forceinline__ float frcp(float x) {
#if __has_builtin(__builtin_amdgcn_rcpf)
  return __builtin_amdgcn_rcpf(x);
#else
  return 1.0f / x;
#endif
}
__device__ __forceinline__ float rfl(float x) {
  return __int_as_float(__builtin_amdgcn_readfirstlane(__float_as_int(x)));
}

typedef __attribute__((address_space(3))) uint32_t lds_u32;
typedef const __attribute__((address_space(1))) uint32_t g_u32;

// ---------------- A: class sums, per-wave independent --------------------
// wave w: row t_base+w -> LDS floats [w*2048, w*2048+2048); float4 slot
// j=64k+lane (clamped dups land in slots 500..511, never read).
// red[w][s] reuses dup slots: float w*2048 + 2000 + s (written post-drain).
__global__ __launch_bounds__(256) void k1_classsum(const float* __restrict__ X,
                                                   float* __restrict__ sig) {
  __shared__ __align__(16) float xrow[8192];   // 32 KB = 4 waves x 8 KB
  const int tid = threadIdx.x;
  const int w = tid >> 6, lane = tid & 63;
  const int t_base = blockIdx.x * 4;
  const size_t rowf4 = (size_t)(t_base + w) * 500;   // float4 units
  const float4* Xv = (const float4*)X;
#pragma unroll
  for (int k = 0; k < 8; ++k) {
    int j = 64 * k + lane;
    j = (j > 499) ? 499 : j;                   // dup -> unused LDS slots
    unsigned ldsoff = (unsigned)(w * 8192 + k * 1024);   // wave-uniform base
    __builtin_amdgcn_global_load_lds(
        (g_u32*)(Xv + rowf4 + (size_t)j),
        (lds_u32*)(uint32_t*)((char*)xrow + ldsoff),
        16, 0, 0);
  }
  asm volatile("s_waitcnt vmcnt(0)" ::: "memory");   // per-wave drain only
  __builtin_amdgcn_sched_barrier(0);

  const float* row = xrow + w * 2048;
  float acc = 0.f;
  if (lane < 60) {
#pragma unroll
    for (int k = 0; k < 33; ++k) acc += row[lane + 60 * k];
  }
  if (lane < 20) acc += row[1980 + lane];
  float a1 = __shfl(acc, (lane + 20 < 64) ? lane + 20 : 63);
  float a2 = __shfl(acc, (lane + 40 < 64) ? lane + 40 : 63);
  if (lane < 20) xrow[w * 2048 + 2000 + lane] = acc + a1 + a2;
  __syncthreads();
  if (w == 0 && lane < 20) {
    float4 o;
    o.x = xrow[2000 + lane];
    o.y = xrow[2048 + 2000 + lane];
    o.z = xrow[4096 + 2000 + lane];
    o.w = xrow[6144 + 2000 + lane];
    *(float4*)(sig + (size_t)lane * T_LEN + t_base) = o;   // t_base % 4 == 0
  }
}

// ---------------- B: fused conv + chunked tree scan (r8 verbatim) --------
__global__ __launch_bounds__(256) void k23_fused(
    const float* __restrict__ sig, const float* __restrict__ V_o,
    const float* __restrict__ K_syn, const float* __restrict__ sbt,
    const float* __restrict__ Delta, const float* __restrict__ C,
    const float* __restrict__ Theta, const float* __restrict__ thresh,
    const float* __restrict__ tscale, const float* __restrict__ ssize,
    const float* __restrict__ hbt, const float* __restrict__ K_hist,
    float* __restrict__ out) {
  __shared__ __align__(16) float sigw[SUBS * SGP];     // 24640 B
  __shared__ __align__(16) float kern[SUBS * KP];      // 16640 B
  __shared__ __align__(16) float lds_subT[SUBS * LPITCH];  // 8000 B
  const int tid = threadIdx.x;
  const int b = blockIdx.x;
  const int t_start = b * CHUNK - WARM;      // multiple of 4

  // ---- stage sig window: rows s, cols [t_start-116, t_start+192) ----
  {
    const int col0 = t_start - 116;          // multiple of 4
    for (int i = tid; i < SUBS * 77; i += 256) {
      int s = i / 77, f4 = i - s * 77;
      int col = col0 + 4 * f4;
      float4 v = {0.f, 0.f, 0.f, 0.f};
      if (col >= 0 && col < T_LEN)
        v = *(const float4*)(sig + (size_t)s * T_LEN + col);
      *(float4*)&sigw[s * SGP + 4 * f4] = v;
    }
  }
  // ---- build per-subunit kernels ----
  {
    const float delta = __expf(Delta[0]);
    const float it0 = __expf(-sbt[0]);
    const float it1 = __expf(-sbt[1]);
    for (int i = tid; i < SUBS * KP; i += 256) {
      int s = i / KP, k = i - s * KP;
      float val = 0.f;
      if (k < KLEN) {
        int c = (s % 5 == 0) ? 1 : 0;
        float te = fmaxf((float)k - delta, 0.f);
        float ta = te * it0, tb = te * it1;
        val = K_syn[s * 4 + c] * (ta * __expf(-ta)) +
              K_syn[s * 4 + 2 + c] * (tb * __expf(-tb));
      }
      kern[i] = val;
    }
  }
  __syncthreads();

  // ---- conv: 500 items (s-major: item = s*25+q), 4 outputs each ----
#pragma unroll
  for (int pass = 0; pass < 2; ++pass) {
    int it = tid + 256 * pass;
    if (it < 500) {
      int s = it / 25, q = it - s * 25;
      const float4* wvs = (const float4*)&sigw[s * SGP];
      const float4* kern4 = (const float4*)&kern[s * KP];
      float4 qA = wvs[q], qB = wvs[q + 1];
      float a0 = 0.f, a1 = 0.f, a2 = 0.f, a3 = 0.f;
#pragma unroll
      for (int g = 0; g < 51; ++g) {
        float4 kv = kern4[g];
        float4 qC = wvs[q + g + 2];
        a0 = fmaf(kv.x, qA.x, fmaf(kv.y, qA.y, fmaf(kv.z, qA.z, fmaf(kv.w, qA.w, a0))));
        a1 = fmaf(kv.x, qA.y, fmaf(kv.y, qA.z, fmaf(kv.z, qA.w, fmaf(kv.w, qB.x, a1))));
        a2 = fmaf(kv.x, qA.z, fmaf(kv.y, qA.w, fmaf(kv.z, qB.x, fmaf(kv.w, qB.y, a2))));
        a3 = fmaf(kv.x, qA.w, fmaf(kv.y, qB.x, fmaf(kv.z, qB.y, fmaf(kv.w, qB.z, a3))));
        qA = qB; qB = qC;
      }
      float4 o; o.x = a0; o.y = a1; o.z = a2; o.w = a3;
      *(float4*)&lds_subT[s * LPITCH + 4 * q] = o;   // rows [t_start-16+4q ..]
    }
  }
  __syncthreads();

  // ---- scan: threads 0..63, proven STEP body ----
  if (tid < 64) {
    const int lane = tid;
    const int s = (lane < SUBS) ? lane : SUBS - 1;
    const float Vo = V_o[0];
    const float L2E = 1.4426950408889634f;
    float eC = __expf(C[s]);
    float szC = ssize[s];
    const float thL = Theta[s] * L2E;
    const float aspk = -tscale[s] * L2E;
    const float bspk = thresh[s] * L2E;
    float k0 = K_hist[s * 3 + 0], k1 = K_hist[s * 3 + 1], k2 = K_hist[s * 3 + 2];
    if (lane >= SUBS) { eC = 0.f; k0 = 0.f; k1 = 0.f; k2 = 0.f; }
    szC *= eC;
    float rho0, rho1, rho2, rt0, rt1, rt2;
    {
      float it, rr;
      it = __expf(-hbt[0]); rr = __expf(-it); rho0 = rfl(rr); rt0 = rfl(rr * it);
      it = __expf(-hbt[1]); rr = __expf(-it); rho1 = rfl(rr); rt1 = rfl(rr * it);
      it = __expf(-hbt[2]); rr = __expf(-it); rho2 = rfl(rr); rt2 = rfl(rr * it);
    }
    const int d = 31 - __clz(s + 1);           // depth 0..4
    const int skew = 4 * (4 - d);              // root 16, leaves 0
    const int cl = (2 * lane + 1 < 64) ? 2 * lane + 1 : 63;
    const int cr = (2 * lane + 2 < 64) ? 2 * lane + 2 : 63;
    int t = t_start - skew;

    float F0 = 0, F1 = 0, F2 = 0, G0 = 0, G1 = 0, G2 = 0;
    float pL0 = 0, pL1 = 0, pL2 = 0, pL3 = 0;
    float pR0 = 0, pR1 = 0, pR2 = 0, pR3 = 0;
    float nL0, nL1, nL2, nL3, nR0, nR1, nR2, nR3;
    const int subbase = s * LPITCH + (16 - skew);   // mult of 4: aligned
    float4 subq = *(const float4*)&lds_subT[subbase];

#define STEP(J, SUBV, PLV, PRV)                                             \
  {                                                                         \
    float conv = fmaf(k0, F0, fmaf(k1, F1, k2 * F2));                       \
    float pre = (SUBV + conv) + (PLV + PRV);                                \
    float u = fexp2(fmaf(pre, -L2E, thL));                                  \
    float post = frcp(1.f + u);                                             \
    float v = fexp2(fmaf(post, aspk, bspk));                                \
    float spk = frcp(1.f + v);                                              \
    spk = ((t + J) < 0) ? 0.f : spk;                                        \
    F0 = fmaf(rho0, F0, rt0 * G0);                                          \
    F1 = fmaf(rho1, F1, rt1 * G1);                                          \
    F2 = fmaf(rho2, F2, rt2 * G2);                                          \
    G0 = fmaf(rho0, G0, spk);                                               \
    G1 = fmaf(rho1, G1, spk);                                               \
    G2 = fmaf(rho2, G2, spk);                                               \
    float y = fmaf(spk, szC, post * eC);                                    \
    if ((n + J) >= OUT_N0) {                                                \
      if (lane == 0) out[t + J] = y + Vo;                                   \
    }                                                                       \
    nL##J = __shfl(y, cl);                                                  \
    nR##J = __shfl(y, cr);                                                  \
  }

    for (int n4 = 0; n4 < NQUAD; ++n4) {
      const int n = n4 << 2;
      float4 subq_n = *(const float4*)&lds_subT[subbase + n + 4];
      STEP(0, subq.x, pL0, pR0)
      STEP(1, subq.y, pL1, pR1)
      STEP(2, subq.z, pL2, pR2)
      STEP(3, subq.w, pL3, pR3)
      subq = subq_n;
      pL0 = nL0; pL1 = nL1; pL2 = nL2; pL3 = nL3;
      pR0 = nR0; pR1 = nR1; pR2 = nR2; pR3 = nR3;
      t += 4;
    }
#undef STEP
  }
}

extern "C" void kernel_launch(void* const* d_in, const int* in_sizes, int n_in,
                              void* d_out, int out_size, void* d_ws, size_t ws_size,
                              hipStream_t stream) {
  (void)in_sizes; (void)n_in; (void)out_size; (void)ws_size;
  const float* X      = (const float*)d_in[0];
  const float* V_o    = (const float*)d_in[1];
  const float* K_syn  = (const float*)d_in[2];
  const float* sbt    = (const float*)d_in[3];
  const float* Delta  = (const float*)d_in[4];
  const float* C      = (const float*)d_in[5];
  const float* Theta  = (const float*)d_in[6];
  const float* thr    = (const float*)d_in[7];
  const float* tsc    = (const float*)d_in[8];
  const float* ssz    = (const float*)d_in[9];
  const float* hbt    = (const float*)d_in[10];
  const float* K_hist = (const float*)d_in[11];
  float* out = (float*)d_out;
  float* sig = (float*)((char*)d_ws + 800000);        // 800000 B

  hipLaunchKernelGGL(k1_classsum, dim3(T_LEN / 4), dim3(256), 0, stream, X, sig);
  hipLaunchKernelGGL(k23_fused, dim3(NBLK), dim3(256), 0, stream,
                     sig, V_o, K_syn, sbt, Delta, C, Theta, thr, tsc, ssz,
                     hbt, K_hist, out);
}